// Round 1
// baseline (1831.545 us; speedup 1.0000x reference)
//
#include <hip/hip_runtime.h>

#define HID 256

typedef __attribute__((ext_vector_type(8))) short short8;
typedef __attribute__((ext_vector_type(4))) float floatx4;

// round-to-nearest-even fp32 -> bf16 (bits in a short)
__device__ __forceinline__ short f2bf(float f) {
  unsigned u = __float_as_uint(f);
  unsigned r = (u + 0x7fffu + ((u >> 16) & 1u)) >> 16;
  return (short)r;
}

// tanh(v) = 1 - 2/(exp(2v)+1); exact limits at +-inf of exp
__device__ __forceinline__ float tanh_fast(float v) {
  float e = __expf(2.0f * v);
  return 1.0f - 2.0f * __builtin_amdgcn_rcpf(e + 1.0f);
}

// ---------------------------------------------------------------------------
// Kernel 1: gate[i] = tanh(x[i,:] @ W1 + b1) @ W2 + b2
// 16x16x32 bf16 MFMA. W1 (256x128) staged in LDS as bf16 in B-fragment order:
// block (ntile, kstep) of 64 lanes x 16B, so each lane does ds_read_b128 at
// lane*16 -> conflict-free. A frags come straight from global: lane holds
// row (lane&15), k = quad*8 + j within each 32-k step (two dwordx4 per step).
// D layout: col(n) = lane&15, row(m) = quad*4 + reg  [m89-verified].
// ---------------------------------------------------------------------------
__global__ __launch_bounds__(256, 2)
void gate_kernel(const float* __restrict__ x, const float* __restrict__ W1,
                 const float* __restrict__ B1, const float* __restrict__ W2,
                 const float* __restrict__ B2, float* __restrict__ gate, int N) {
  __shared__ __align__(16) short sW1[32768];  // 64 KB, exactly W1 in bf16

  const int tid = threadIdx.x;

  // stage W1 fp32 [k=256][n=128] -> swizzled bf16 fragment layout
  for (int idx = tid; idx < 32768; idx += 256) {
    int k = idx >> 7, n = idx & 127;
    int lane_s = (n & 15) | (((k >> 3) & 3) << 4);         // frag lane
    int pos = (((n >> 4) * 8 + (k >> 5)) * 64 + lane_s) * 8 + (k & 7);
    sW1[pos] = f2bf(W1[idx]);
  }
  __syncthreads();

  const int lane = tid & 63;
  const int quad = lane >> 4;   // 0..3
  const int r16  = lane & 15;

  // per-lane layer-2 constants: n = nt*16 + r16
  float b1v[8], w2v[8];
#pragma unroll
  for (int nt = 0; nt < 8; ++nt) {
    b1v[nt] = B1[nt * 16 + r16];
    w2v[nt] = W2[nt * 16 + r16];
  }
  const float b2v = B2[0];

  const short8* bfr = (const short8*)sW1;
  const int gwave  = blockIdx.x * 4 + (tid >> 6);
  const int nWaves = gridDim.x * 4;
  const int ntiles = (N + 15) >> 4;

  float4 xa[16];
  auto preload = [&](int t) {
    int row = t * 16 + r16;
    if (row >= N) row = N - 1;  // tail clamp (unused rows never stored)
    const float4* xr = (const float4*)(x + (size_t)row * HID) + quad * 2;
#pragma unroll
    for (int s = 0; s < 8; ++s) {
      xa[2 * s]     = xr[s * 8];
      xa[2 * s + 1] = xr[s * 8 + 1];
    }
  };

  int tile = gwave;
  if (tile < ntiles) preload(tile);

  for (; tile < ntiles; tile += nWaves) {
    // convert current tile's A to bf16 frags
    short8 af[8];
#pragma unroll
    for (int s = 0; s < 8; ++s) {
      float4 u = xa[2 * s], v = xa[2 * s + 1];
      short8 a = {f2bf(u.x), f2bf(u.y), f2bf(u.z), f2bf(u.w),
                  f2bf(v.x), f2bf(v.y), f2bf(v.z), f2bf(v.w)};
      af[s] = a;
    }
    // software-pipeline: issue next tile's global loads now
    int nxt = tile + nWaves;
    if (nxt < ntiles) preload(nxt);

    floatx4 acc[8];
#pragma unroll
    for (int nt = 0; nt < 8; ++nt) acc[nt] = (floatx4){0.f, 0.f, 0.f, 0.f};

#pragma unroll
    for (int s = 0; s < 8; ++s) {
#pragma unroll
      for (int nt = 0; nt < 8; ++nt) {
        short8 bf = bfr[(nt * 8 + s) * 64 + lane];
        acc[nt] = __builtin_amdgcn_mfma_f32_16x16x32_bf16(af[s], bf, acc[nt], 0, 0, 0);
      }
    }

    // layer 2: p[r] = sum_n tanh(h + b1[n]) * W2[n], n split across 16 lanes
    float p0 = 0.f, p1 = 0.f, p2 = 0.f, p3 = 0.f;
#pragma unroll
    for (int nt = 0; nt < 8; ++nt) {
      float bb = b1v[nt], ww = w2v[nt];
      p0 = fmaf(tanh_fast(acc[nt][0] + bb), ww, p0);
      p1 = fmaf(tanh_fast(acc[nt][1] + bb), ww, p1);
      p2 = fmaf(tanh_fast(acc[nt][2] + bb), ww, p2);
      p3 = fmaf(tanh_fast(acc[nt][3] + bb), ww, p3);
    }
    // butterfly-sum across the 16 lanes of this quad group
#pragma unroll
    for (int off = 1; off < 16; off <<= 1) {
      p0 += __shfl_xor(p0, off, 64);
      p1 += __shfl_xor(p1, off, 64);
      p2 += __shfl_xor(p2, off, 64);
      p3 += __shfl_xor(p3, off, 64);
    }
    if (r16 == 0) {
      int node0 = tile * 16 + quad * 4;
      if (node0 + 4 <= N) {
        float4 gv = {p0 + b2v, p1 + b2v, p2 + b2v, p3 + b2v};
        *(float4*)(gate + node0) = gv;
      } else {
        float gv[4] = {p0 + b2v, p1 + b2v, p2 + b2v, p3 + b2v};
        for (int r = 0; r < 4; ++r)
          if (node0 + r < N) gate[node0 + r] = gv[r];
      }
    }
  }
}

// ---------------------------------------------------------------------------
// Kernel 2: per-graph softmax over gates + weighted feature sum.
// batch is sorted -> graph g's nodes are a contiguous [start, end) found by
// binary search. One block per graph, thread t owns output column t.
// Normalization deferred: out = (sum e_i * x_i) / (sum e_i + 1e-16).
// ---------------------------------------------------------------------------
__global__ __launch_bounds__(256)
void readout_kernel(const float* __restrict__ x, const float* __restrict__ gate,
                    const int* __restrict__ batch, float* __restrict__ out, int N) {
  const int g = blockIdx.x;
  const int t = threadIdx.x;
  __shared__ int sRange[2];
  __shared__ float sred[4];
  __shared__ float sM;

  if (t < 2) {
    int target = g + t;
    int lo = 0, hi = N;
    while (lo < hi) {
      int mid = (lo + hi) >> 1;
      if (batch[mid] < target) lo = mid + 1; else hi = mid;
    }
    sRange[t] = lo;
  }
  __syncthreads();
  const int start = sRange[0], end = sRange[1];

  // block max of gate[start:end]
  float lm = -INFINITY;
  for (int i = start + t; i < end; i += 256) lm = fmaxf(lm, gate[i]);
#pragma unroll
  for (int off = 32; off >= 1; off >>= 1) lm = fmaxf(lm, __shfl_xor(lm, off, 64));
  if ((t & 63) == 0) sred[t >> 6] = lm;
  __syncthreads();
  if (t == 0) sM = fmaxf(fmaxf(sred[0], sred[1]), fmaxf(sred[2], sred[3]));
  __syncthreads();
  const float m = sM;

  // single pass: unnormalized weighted sum + denominator (same in all threads)
  float acc = 0.f, s = 0.f;
  const float* xp = x + (size_t)start * HID + t;
  int i = start;
  for (; i + 4 <= end; i += 4, xp += 4 * HID) {
    float g0 = gate[i], g1 = gate[i + 1], g2 = gate[i + 2], g3 = gate[i + 3];
    float x0 = xp[0], x1 = xp[HID], x2 = xp[2 * HID], x3 = xp[3 * HID];
    float e0 = __expf(g0 - m), e1 = __expf(g1 - m);
    float e2 = __expf(g2 - m), e3 = __expf(g3 - m);
    s += (e0 + e1) + (e2 + e3);
    acc = fmaf(e0, x0, acc);
    acc = fmaf(e1, x1, acc);
    acc = fmaf(e2, x2, acc);
    acc = fmaf(e3, x3, acc);
  }
  for (; i < end; ++i, xp += HID) {
    float e = __expf(gate[i] - m);
    s += e;
    acc = fmaf(e, xp[0], acc);
  }
  out[(size_t)g * HID + t] = acc / (s + 1e-16f);
}

extern "C" void kernel_launch(void* const* d_in, const int* in_sizes, int n_in,
                              void* d_out, int out_size, void* d_ws, size_t ws_size,
                              hipStream_t stream) {
  const float* x   = (const float*)d_in[0];
  const float* W1  = (const float*)d_in[1];
  const float* b1  = (const float*)d_in[2];
  const float* W2  = (const float*)d_in[3];
  const float* b2  = (const float*)d_in[4];
  const int*  batch = (const int*)d_in[5];
  float* out  = (float*)d_out;
  float* gate = (float*)d_ws;          // N floats = 4 MB scratch

  const int N = in_sizes[0] / HID;     // 1,000,000
  const int G = out_size / HID;        // 8192

  gate_kernel<<<512, 256, 0, stream>>>(x, W1, b1, W2, b2, gate, N);
  readout_kernel<<<G, 256, 0, stream>>>(x, gate, batch, out, N);
}